// Round 6
// baseline (392.078 us; speedup 1.0000x reference)
//
#include <hip/hip_runtime.h>
#include <hip/hip_bf16.h>
#include <stdint.h>

#define NDIM 512
#define NN (NDIM*NDIM)      // 262144 positions
#define CDIM 128
#define LDSP 136            // padded LDS stride (bf16 elems): 272B, 16B-mult

typedef __attribute__((ext_vector_type(8))) short short8;
typedef __attribute__((ext_vector_type(4))) short short4v;
typedef __attribute__((ext_vector_type(4))) float f32x4;

__device__ __forceinline__ unsigned short f2bf(float f) {
    union { float f; uint32_t u; } v; v.f = f;
    uint32_t u = v.u;
    return (unsigned short)((u + 0x7FFFu + ((u >> 16) & 1u)) >> 16);
}
__device__ __forceinline__ float bf2f(unsigned short b) {
    union { uint32_t u; float f; } v; v.u = ((uint32_t)b) << 16;
    return v.f;
}
__device__ __forceinline__ f32x4 mfma16(short8 a, short8 b, f32x4 c) {
    return __builtin_amdgcn_mfma_f32_16x16x32_bf16(a, b, c, 0, 0, 0);
}
__device__ __forceinline__ void gl_lds16(const void* g, void* l) {
    __builtin_amdgcn_global_load_lds((const __attribute__((address_space(1))) void*)g,
                                     (__attribute__((address_space(3))) void*)l,
                                     16, 0, 0);
}

// ---------------- K0: weight prep (f32 -> bf16, transposed [col][k]) -------------
__global__ void k0_prep(const float* __restrict__ w_ag, const float* __restrict__ w_ap,
                        const float* __restrict__ w_bg, const float* __restrict__ w_bp,
                        const float* __restrict__ w_g,  const float* __restrict__ w_o,
                        unsigned short* __restrict__ Wcat, unsigned short* __restrict__ Wo_t)
{
    int idx = blockIdx.x * 256 + threadIdx.x;
    if (idx < 640*128) {
        int col = idx >> 7, k = idx & 127;
        int s = col >> 7, h = col & 127;
        const float* w = (s==0) ? w_ag : (s==1) ? w_ap : (s==2) ? w_bg : (s==3) ? w_bp : w_g;
        Wcat[idx] = f2bf(w[k*128 + h]);            // Wcat[(s*128+h)][k] = w_s[k][h]
    } else if (idx < 640*128 + 128*128) {
        int i2 = idx - 640*128;
        int cc = i2 >> 7, h = i2 & 127;
        Wo_t[i2] = f2bf(w_o[h*128 + cc]);          // Wo_t[c][h] = w_o[h][c]
    }
}

// ---------------- K1: LN_in + 5 projections + activations ------------------------
// out: a_t[c][pos], b_t[c][pos] (channel-major); g_out[pos][c] (round-1 layout)
__global__ __launch_bounds__(256, 4) void k1_proj(
    const float* __restrict__ z, const float* __restrict__ mask,
    const float* __restrict__ lnw, const float* __restrict__ lnb,
    const unsigned short* __restrict__ Wcat,
    const float* __restrict__ b_ag, const float* __restrict__ b_ap,
    const float* __restrict__ b_bg, const float* __restrict__ b_bp,
    const float* __restrict__ b_g,
    unsigned short* __restrict__ a_t, unsigned short* __restrict__ b_t,
    unsigned short* __restrict__ g_out)
{
    __shared__ unsigned short zb[128*LDSP];   // LN'd z [row][k]; reused as g transpose buf
    __shared__ float mask_s[128];
    __shared__ float lnw_s[128];
    __shared__ float lnb_s[128];
    __shared__ float bias_s[640];

    const int t = threadIdx.x;
    const int pos0 = blockIdx.x * 128;
    const int tid2 = t >> 1, half = t & 1;
    const int wave = t >> 6, lane = t & 63;
    const int lr = lane & 15, lh = lane >> 4;

    if (t < 128) {
        lnw_s[t] = lnw[t];
        lnb_s[t] = lnb[t];
        mask_s[t] = mask[pos0 + t];
    }
    for (int i = t; i < 640; i += 256) {
        int s = i >> 7, c = i & 127;
        const float* bp = (s==0) ? b_ag : (s==1) ? b_ap : (s==2) ? b_bg : (s==3) ? b_bp : b_g;
        bias_s[i] = bp[c];
    }

    // ---- load z (2 threads per row), LN over C ----
    float v[64];
    float s0 = 0.f, s1 = 0.f;
    {
        const float* zr = z + (size_t)(pos0 + tid2) * CDIM + half * 64;
        #pragma unroll
        for (int i = 0; i < 16; i++) {
            float4 q = *(const float4*)(zr + i*4);
            v[i*4+0] = q.x; v[i*4+1] = q.y; v[i*4+2] = q.z; v[i*4+3] = q.w;
        }
        #pragma unroll
        for (int i = 0; i < 64; i++) { s0 += v[i]; s1 += v[i]*v[i]; }
        s0 += __shfl_xor(s0, 1);
        s1 += __shfl_xor(s1, 1);
    }
    __syncthreads();   // lnw_s/lnb_s/bias/mask ready
    {
        float m  = s0 * (1.f/128.f);
        float va = s1 * (1.f/128.f) - m*m;
        float rs = rsqrtf(va + 1e-5f);
        #pragma unroll
        for (int i = 0; i < 8; i++) {
            short8 pk;
            #pragma unroll
            for (int j = 0; j < 8; j++) {
                int c = half*64 + i*8 + j;
                pk[j] = (short)f2bf((v[i*8+j]-m)*rs*lnw_s[c] + lnb_s[c]);
            }
            *(short8*)&zb[tid2*LDSP + half*64 + i*8] = pk;
        }
    }
    __syncthreads();   // zb ready

    const int rowA0 = (wave*32 + lr)*LDSP;
    const int rowA1 = (wave*32 + 16 + lr)*LDSP;

    // GEMM over a 64-col half of one weight matrix: acc[2][4]
    auto gemmh = [&](int s, int h, f32x4 (&acc)[2][4]) {
        #pragma unroll
        for (int m = 0; m < 2; m++)
            #pragma unroll
            for (int n = 0; n < 4; n++) { f32x4 zz = {0.f,0.f,0.f,0.f}; acc[m][n] = zz; }
        #pragma unroll
        for (int kk = 0; kk < 4; kk++) {
            const int k0 = kk*32 + lh*8;
            short8 af0 = *(const short8*)&zb[rowA0 + k0];
            short8 af1 = *(const short8*)&zb[rowA1 + k0];
            #pragma unroll
            for (int n = 0; n < 4; n++) {
                int col = h*64 + n*16 + lr;
                short8 bf = *(const short8*)&Wcat[(size_t)(s*128 + col)*128 + k0];
                acc[0][n] = mfma16(af0, bf, acc[0][n]);
                acc[1][n] = mfma16(af1, bf, acc[1][n]);
            }
        }
    };

    // gated pair -> dst[c][pos] (channel-major), 8B per lane per (m,n)
    auto pair_half = [&](int sG, int sP, int h, unsigned short* dstg) {
        f32x4 G[2][4], P[2][4];
        gemmh(sG, h, G);
        gemmh(sP, h, P);
        #pragma unroll
        for (int m = 0; m < 2; m++) {
            int rb = wave*32 + m*16 + lh*4;
            #pragma unroll
            for (int n = 0; n < 4; n++) {
                int col = h*64 + n*16 + lr;
                float bgv = bias_s[sG*128 + col];
                float bpv = bias_s[sP*128 + col];
                short4v pk;
                #pragma unroll
                for (int r = 0; r < 4; r++) {
                    float gate = 1.f / (1.f + __expf(-(G[m][n][r] + bgv)));
                    float proj = P[m][n][r] + bpv;
                    pk[r] = (short)f2bf(mask_s[rb + r] * gate * proj);
                }
                *(short4v*)(dstg + (size_t)col*NN + pos0 + rb) = pk;
            }
        }
    };

    pair_half(0, 1, 0, a_t);
    pair_half(0, 1, 1, a_t);
    pair_half(2, 3, 0, b_t);
    pair_half(2, 3, 1, b_t);

    // gate g -> g_out[pos][c] via LDS transpose (round-1 proven path; zb reused)
    f32x4 G0[2][4], G1[2][4];
    gemmh(4, 0, G0);
    gemmh(4, 1, G1);
    __syncthreads();   // all zb reads complete block-wide before overwrite
    #pragma unroll
    for (int m = 0; m < 2; m++) {
        int rb = wave*32 + m*16 + lh*4;
        #pragma unroll
        for (int n = 0; n < 4; n++) {
            int c0 = n*16 + lr;
            int c1 = 64 + n*16 + lr;
            float b0 = bias_s[512 + c0];
            float b1 = bias_s[512 + c1];
            #pragma unroll
            for (int r = 0; r < 4; r++) {
                zb[(rb + r)*LDSP + c0] = f2bf(1.f / (1.f + __expf(-(G0[m][n][r] + b0))));
                zb[(rb + r)*LDSP + c1] = f2bf(1.f / (1.f + __expf(-(G1[m][n][r] + b1))));
            }
        }
    }
    __syncthreads();
    {
        const unsigned short* src = zb + tid2*LDSP + half*64;
        unsigned short* dst = g_out + (size_t)(pos0 + tid2)*CDIM + half*64;
        #pragma unroll
        for (int i = 0; i < 8; i++)
            *(short8*)(dst + i*8) = *(const short8*)(src + i*8);
    }
}

// ---------------- K2: per-channel einsum x[c] = A_c * B_c^T ----------------------
// Round-1 structure verbatim: 128x128 tile, K steps of 64, linear LDS staging.
__global__ __launch_bounds__(256, 2) void k2_einsum(
    const unsigned short* __restrict__ a_t,
    const unsigned short* __restrict__ b_t,
    unsigned short* __restrict__ x_t)
{
    __shared__ unsigned short As[128*64];
    __shared__ unsigned short Bs[128*64];

    const int c  = blockIdx.y;
    const int ti = (blockIdx.x >> 2) * 128;
    const int tj = (blockIdx.x & 3) * 128;
    const int t = threadIdx.x;
    const int wave = t >> 6, lane = t & 63;
    const int lr = lane & 15, lh = lane >> 4;
    const int wm = wave >> 1, wn = wave & 1;

    const unsigned short* Ag = a_t + (size_t)c*NN + (size_t)ti*NDIM;
    const unsigned short* Bg = b_t + (size_t)c*NN + (size_t)tj*NDIM;

    const int srow = wave*32 + (lane >> 3);  // staging row within tile
    const int scol = (lane & 7) * 8;         // staging k-offset (elems)

    f32x4 acc[4][4] = {};

    for (int k0 = 0; k0 < NDIM; k0 += 64) {
        __syncthreads();
        #pragma unroll
        for (int it = 0; it < 4; it++) {
            int r = srow + it*8;
            gl_lds16(Ag + (size_t)r*NDIM + k0 + scol, (void*)(As + (wave*32 + it*8)*64));
            gl_lds16(Bg + (size_t)r*NDIM + k0 + scol, (void*)(Bs + (wave*32 + it*8)*64));
        }
        asm volatile("s_waitcnt vmcnt(0)" ::: "memory");
        __syncthreads();
        #pragma unroll
        for (int kk = 0; kk < 2; kk++) {
            const int kof = kk*32 + lh*8;
            short8 af[4], bfr[4];
            #pragma unroll
            for (int m = 0; m < 4; m++)
                af[m] = *(const short8*)&As[(wm*64 + m*16 + lr)*64 + kof];
            #pragma unroll
            for (int n = 0; n < 4; n++)
                bfr[n] = *(const short8*)&Bs[(wn*64 + n*16 + lr)*64 + kof];
            #pragma unroll
            for (int m = 0; m < 4; m++)
                #pragma unroll
                for (int n = 0; n < 4; n++)
                    acc[m][n] = mfma16(af[m], bfr[n], acc[m][n]);
        }
    }

    #pragma unroll
    for (int m = 0; m < 4; m++) {
        int row = ti + wm*64 + m*16 + lh*4;
        #pragma unroll
        for (int n = 0; n < 4; n++) {
            int col = tj + wn*64 + n*16 + lr;
            unsigned short* dst = x_t + (size_t)c*NN + (size_t)row*NDIM + col;
            #pragma unroll
            for (int r = 0; r < 4; r++)
                dst[(size_t)r*NDIM] = f2bf(acc[m][n][r]);
        }
    }
}

// ---------------- K3: LN_out + output projection + gate (round-1 verbatim) -------
__global__ __launch_bounds__(256, 2) void k3_out(
    const unsigned short* __restrict__ x_t,
    const unsigned short* __restrict__ g_in,
    const unsigned short* __restrict__ Wo_t,
    const float* __restrict__ lnw, const float* __restrict__ lnb,
    const float* __restrict__ b_o,
    float* __restrict__ out)
{
    __shared__ unsigned short xb[128*LDSP];   // x tile [c][pos]; reused for Wo [col][k]
    __shared__ unsigned short zl[128*LDSP];   // LN'd x [pos][c]; reused for g [pos][c]
    __shared__ float lnw_s[128];
    __shared__ float lnb_s[128];
    __shared__ float bo_s[128];

    const int t = threadIdx.x;
    const int pos0 = blockIdx.x * 128;
    const int tid2 = t >> 1, half = t & 1;
    const int wave = t >> 6, lane = t & 63;
    const int lr = lane & 15, lh = lane >> 4;

    if (t < 128) { lnw_s[t] = lnw[t]; lnb_s[t] = lnb[t]; bo_s[t] = b_o[t]; }

    // stage x tile: thread pair per channel row, coalesced
    {
        const unsigned short* src = x_t + (size_t)tid2*NN + pos0 + half*64;
        unsigned short* dst = xb + tid2*LDSP + half*64;
        #pragma unroll
        for (int i = 0; i < 8; i++)
            *(short8*)(dst + i*8) = *(const short8*)(src + i*8);
    }
    __syncthreads();

    // LN over c: 2 threads per pos
    {
        float v[64];
        float s0 = 0.f, s1 = 0.f;
        #pragma unroll
        for (int i = 0; i < 64; i++) {
            float x = bf2f(xb[(half*64 + i)*LDSP + tid2]);
            v[i] = x; s0 += x; s1 += x*x;
        }
        s0 += __shfl_xor(s0, 1);
        s1 += __shfl_xor(s1, 1);
        float m  = s0 * (1.f/128.f);
        float va = s1 * (1.f/128.f) - m*m;
        float rs = rsqrtf(va + 1e-5f);
        #pragma unroll
        for (int i = 0; i < 64; i++) {
            int cc = half*64 + i;
            zl[tid2*LDSP + cc] = f2bf((v[i]-m)*rs*lnw_s[cc] + lnb_s[cc]);
        }
    }
    __syncthreads();

    // Wo into xb (alias; xb dead now)
    {
        const unsigned short* src = Wo_t + ((size_t)tid2*128 + half*64);
        unsigned short* dst = xb + tid2*LDSP + half*64;
        #pragma unroll
        for (int i = 0; i < 8; i++)
            *(short8*)(dst + i*8) = *(const short8*)(src + i*8);
    }
    __syncthreads();

    f32x4 acc[2][8];
    #pragma unroll
    for (int m = 0; m < 2; m++)
        #pragma unroll
        for (int n = 0; n < 8; n++) { f32x4 zz = {0.f,0.f,0.f,0.f}; acc[m][n] = zz; }

    #pragma unroll
    for (int kk = 0; kk < 4; kk++) {
        const int k0 = kk*32 + lh*8;
        short8 af0 = *(const short8*)&zl[(wave*32 + lr)*LDSP + k0];
        short8 af1 = *(const short8*)&zl[(wave*32 + 16 + lr)*LDSP + k0];
        #pragma unroll
        for (int n = 0; n < 8; n++) {
            short8 bf = *(const short8*)&xb[(n*16 + lr)*LDSP + k0];
            acc[0][n] = mfma16(af0, bf, acc[0][n]);
            acc[1][n] = mfma16(af1, bf, acc[1][n]);
        }
    }
    __syncthreads();

    // g into zl space (zl dead after GEMM)
    {
        const unsigned short* src = g_in + (size_t)(pos0 + tid2)*CDIM + half*64;
        unsigned short* dst = zl + tid2*LDSP + half*64;
        #pragma unroll
        for (int i = 0; i < 8; i++)
            *(short8*)(dst + i*8) = *(const short8*)(src + i*8);
    }
    __syncthreads();

    #pragma unroll
    for (int m = 0; m < 2; m++) {
        int rb = wave*32 + m*16 + lh*4;
        #pragma unroll
        for (int n = 0; n < 8; n++) {
            int col = n*16 + lr;
            float bo = bo_s[col];
            #pragma unroll
            for (int r = 0; r < 4; r++) {
                int row = rb + r;
                float gv = bf2f(zl[row*LDSP + col]);
                out[(size_t)(pos0 + row)*CDIM + col] = gv * (acc[m][n][r] + bo);
            }
        }
    }
}

// ---------------- launcher -------------------------------------------------------
extern "C" void kernel_launch(void* const* d_in, const int* in_sizes, int n_in,
                              void* d_out, int out_size, void* d_ws, size_t ws_size,
                              hipStream_t stream) {
    const float* z        = (const float*)d_in[0];
    const float* mask     = (const float*)d_in[1];
    const float* ln_in_w  = (const float*)d_in[2];
    const float* ln_in_b  = (const float*)d_in[3];
    const float* w_ap     = (const float*)d_in[4];
    const float* b_ap     = (const float*)d_in[5];
    const float* w_ag     = (const float*)d_in[6];
    const float* b_ag     = (const float*)d_in[7];
    const float* w_bp     = (const float*)d_in[8];
    const float* b_bp     = (const float*)d_in[9];
    const float* w_bg     = (const float*)d_in[10];
    const float* b_bg     = (const float*)d_in[11];
    const float* ln_out_w = (const float*)d_in[12];
    const float* ln_out_b = (const float*)d_in[13];
    const float* w_o      = (const float*)d_in[14];
    const float* b_o      = (const float*)d_in[15];
    const float* w_g      = (const float*)d_in[16];
    const float* b_g      = (const float*)d_in[17];

    char* ws = (char*)d_ws;
    const size_t BUF = (size_t)NN * 128 * 2;      // 64 MB per bf16 buffer
    unsigned short* a_t  = (unsigned short*)(ws);
    unsigned short* b_t  = (unsigned short*)(ws + BUF);
    unsigned short* g_b  = (unsigned short*)(ws + 2*BUF);
    unsigned short* x_t  = (unsigned short*)(ws + 3*BUF);
    unsigned short* Wcat = (unsigned short*)(ws + 4*BUF);
    unsigned short* Wo_t = (unsigned short*)(ws + 4*BUF + 640*128*2);

    k0_prep<<<384, 256, 0, stream>>>(w_ag, w_ap, w_bg, w_bp, w_g, w_o, Wcat, Wo_t);
    k1_proj<<<NN/128, 256, 0, stream>>>(z, mask, ln_in_w, ln_in_b, Wcat,
                                        b_ag, b_ap, b_bg, b_bp, b_g, a_t, b_t, g_b);
    k2_einsum<<<dim3(16, 128), 256, 0, stream>>>(a_t, b_t, x_t);
    k3_out<<<NN/128, 256, 0, stream>>>(x_t, g_b, Wo_t, ln_out_w, ln_out_b, b_o,
                                       (float*)d_out);
}

// Round 7
// 330.930 us; speedup vs baseline: 1.1848x; 1.1848x over previous
//
#include <hip/hip_runtime.h>
#include <hip/hip_bf16.h>
#include <stdint.h>

#define NDIM 512
#define NN (NDIM*NDIM)      // 262144 positions
#define CDIM 128
#define LDSP 136            // padded LDS stride (bf16 elems): 272B, 16B-mult

typedef __attribute__((ext_vector_type(8))) short short8;
typedef __attribute__((ext_vector_type(4))) short short4v;
typedef __attribute__((ext_vector_type(4))) float f32x4;
typedef unsigned long long ull;

__device__ __forceinline__ unsigned short f2bf(float f) {
    union { float f; uint32_t u; } v; v.f = f;
    uint32_t u = v.u;
    return (unsigned short)((u + 0x7FFFu + ((u >> 16) & 1u)) >> 16);
}
__device__ __forceinline__ float bf2f(unsigned short b) {
    union { uint32_t u; float f; } v; v.u = ((uint32_t)b) << 16;
    return v.f;
}
__device__ __forceinline__ f32x4 mfma16(short8 a, short8 b, f32x4 c) {
    return __builtin_amdgcn_mfma_f32_16x16x32_bf16(a, b, c, 0, 0, 0);
}
__device__ __forceinline__ void gl_lds16(const void* g, void* l) {
    __builtin_amdgcn_global_load_lds((const __attribute__((address_space(1))) void*)g,
                                     (__attribute__((address_space(3))) void*)l,
                                     16, 0, 0);
}

// ---------------- K0: weight prep --------------------------------------------
// Wfrag: 5 proj matrices in MFMA-fragment order. Chunk idx = s*2048 + h*1024 +
// kk*256 + n*64 + lane; chunk holds w_s[k0+e][col], col=h*64+n*16+(lane&15),
// k0=kk*32+(lane>>4)*8, e=0..7.  K1 reads chunk-groups as coalesced 1KB/wave.
// Wo_t[c][h] = w_o[h][c] (round-6 layout, consumed by K3 verbatim).
__global__ void k0_prep(const float* __restrict__ w_ag, const float* __restrict__ w_ap,
                        const float* __restrict__ w_bg, const float* __restrict__ w_bp,
                        const float* __restrict__ w_g,  const float* __restrict__ w_o,
                        unsigned short* __restrict__ Wfrag, unsigned short* __restrict__ Wo_t)
{
    int idx = blockIdx.x * 256 + threadIdx.x;
    if (idx < 10240) {
        int lane = idx & 63;
        int n  = (idx >> 6) & 3;
        int kk = (idx >> 8) & 3;
        int h  = (idx >> 10) & 1;
        int s  = idx >> 11;          // 0..4
        const float* w = (s==0) ? w_ag : (s==1) ? w_ap : (s==2) ? w_bg : (s==3) ? w_bp : w_g;
        int col = h*64 + n*16 + (lane & 15);
        int k0  = kk*32 + (lane >> 4)*8;
        short8 pk;
        #pragma unroll
        for (int e = 0; e < 8; e++)
            pk[e] = (short)f2bf(w[(k0 + e)*128 + col]);
        *(short8*)(Wfrag + (size_t)idx*8) = pk;
    } else if (idx < 10240 + 16384) {
        int i2 = idx - 10240;
        int cc = i2 >> 7, hh = i2 & 127;
        Wo_t[i2] = f2bf(w_o[hh*128 + cc]);
    }
}

// ---------------- K1: LN_in + 5 projections + activations ------------------------
// out: a_t[c][pos], b_t[c][pos] (channel-major, shfl write-combined);
//      g_out[pos][c] (round-6 proven LDS-transpose path)
__global__ __launch_bounds__(256, 3) void k1_proj(
    const float* __restrict__ z, const float* __restrict__ mask,
    const float* __restrict__ lnw, const float* __restrict__ lnb,
    const unsigned short* __restrict__ Wfrag,
    const float* __restrict__ b_ag, const float* __restrict__ b_ap,
    const float* __restrict__ b_bg, const float* __restrict__ b_bp,
    const float* __restrict__ b_g,
    unsigned short* __restrict__ a_t, unsigned short* __restrict__ b_t,
    unsigned short* __restrict__ g_out)
{
    __shared__ unsigned short zb[128*LDSP];   // LN'd z [row][k]; reused as g transpose buf
    __shared__ float mask_s[128];
    __shared__ float lnw_s[128];
    __shared__ float lnb_s[128];
    __shared__ float bias_s[640];

    const int t = threadIdx.x;
    const int pos0 = blockIdx.x * 128;
    const int tid2 = t >> 1, half = t & 1;
    const int wave = t >> 6, lane = t & 63;
    const int lr = lane & 15, lh = lane >> 4;

    if (t < 128) {
        lnw_s[t] = lnw[t];
        lnb_s[t] = lnb[t];
        mask_s[t] = mask[pos0 + t];
    }
    for (int i = t; i < 640; i += 256) {
        int s = i >> 7, c = i & 127;
        const float* bp = (s==0) ? b_ag : (s==1) ? b_ap : (s==2) ? b_bg : (s==3) ? b_bp : b_g;
        bias_s[i] = bp[c];
    }

    // ---- load z (2 threads per row), LN over C ----
    float v[64];
    float s0 = 0.f, s1 = 0.f;
    {
        const float* zr = z + (size_t)(pos0 + tid2) * CDIM + half * 64;
        #pragma unroll
        for (int i = 0; i < 16; i++) {
            float4 q = *(const float4*)(zr + i*4);
            v[i*4+0] = q.x; v[i*4+1] = q.y; v[i*4+2] = q.z; v[i*4+3] = q.w;
        }
        #pragma unroll
        for (int i = 0; i < 64; i++) { s0 += v[i]; s1 += v[i]*v[i]; }
        s0 += __shfl_xor(s0, 1);
        s1 += __shfl_xor(s1, 1);
    }
    __syncthreads();   // lnw_s/lnb_s/bias/mask ready
    {
        float m  = s0 * (1.f/128.f);
        float va = s1 * (1.f/128.f) - m*m;
        float rs = rsqrtf(va + 1e-5f);
        #pragma unroll
        for (int i = 0; i < 8; i++) {
            short8 pk;
            #pragma unroll
            for (int j = 0; j < 8; j++) {
                int c = half*64 + i*8 + j;
                pk[j] = (short)f2bf((v[i*8+j]-m)*rs*lnw_s[c] + lnb_s[c]);
            }
            *(short8*)&zb[tid2*LDSP + half*64 + i*8] = pk;
        }
    }
    __syncthreads();   // zb ready

    const int rowA0 = (wave*32 + lr)*LDSP;
    const int rowA1 = (wave*32 + 16 + lr)*LDSP;
    const unsigned short* wfl = Wfrag + (size_t)lane*8;

    // GEMM over a 64-col half of one weight matrix: acc[2][4].
    // B fragments from Wfrag: 1KB coalesced per wave per load, L2-hot.
    auto gemmh = [&](int s, int h, f32x4 (&acc)[2][4]) {
        #pragma unroll
        for (int m = 0; m < 2; m++)
            #pragma unroll
            for (int n = 0; n < 4; n++) { f32x4 zz = {0.f,0.f,0.f,0.f}; acc[m][n] = zz; }
        const unsigned short* wf = wfl + (size_t)(s*2 + h)*8192;
        #pragma unroll
        for (int kk = 0; kk < 4; kk++) {
            const int k0 = kk*32 + lh*8;
            short8 af0 = *(const short8*)&zb[rowA0 + k0];
            short8 af1 = *(const short8*)&zb[rowA1 + k0];
            #pragma unroll
            for (int n = 0; n < 4; n++) {
                short8 bf = *(const short8*)(wf + (kk*4 + n)*512);
                acc[0][n] = mfma16(af0, bf, acc[0][n]);
                acc[1][n] = mfma16(af1, bf, acc[1][n]);
            }
        }
    };

    // gated pair -> dst[c][pos] channel-major; shfl_xor(16) write-combine so each
    // store instr covers full 64B lines per column (no partial-line writes).
    auto pair_half = [&](int sG, int sP, int h, unsigned short* dstg) {
        f32x4 G[2][4], P[2][4];
        gemmh(sG, h, G);
        gemmh(sP, h, P);
        const int odd = lh & 1;
        const int base = wave*32 + lh*4 + (odd ? 12 : 0);
        #pragma unroll
        for (int n = 0; n < 4; n++) {
            int col = h*64 + n*16 + lr;
            float bgv = bias_s[sG*128 + col];
            float bpv = bias_s[sP*128 + col];
            union { short4v v; ull u; } p0, p1;
            #pragma unroll
            for (int r = 0; r < 4; r++) {
                float g0 = 1.f / (1.f + __expf(-(G[0][n][r] + bgv)));
                p0.v[r] = (short)f2bf(mask_s[wave*32 + lh*4 + r] * g0 * (P[0][n][r] + bpv));
                float g1 = 1.f / (1.f + __expf(-(G[1][n][r] + bgv)));
                p1.v[r] = (short)f2bf(mask_s[wave*32 + 16 + lh*4 + r] * g1 * (P[1][n][r] + bpv));
            }
            ull r0 = __shfl_xor(p0.u, 16);
            ull r1 = __shfl_xor(p1.u, 16);
            union { ull u[2]; short8 v; } outv;
            outv.u[0] = odd ? r1 : p0.u;   // rows base..base+3
            outv.u[1] = odd ? p1.u : r0;   // rows base+4..base+7
            *(short8*)(dstg + (size_t)col*NN + pos0 + base) = outv.v;
        }
    };

    pair_half(0, 1, 0, a_t);
    pair_half(0, 1, 1, a_t);
    pair_half(2, 3, 0, b_t);
    pair_half(2, 3, 1, b_t);

    // gate g -> g_out[pos][c] via LDS transpose (round-6 proven path; zb reused)
    f32x4 G0[2][4], G1[2][4];
    gemmh(4, 0, G0);
    gemmh(4, 1, G1);
    __syncthreads();   // all zb reads complete block-wide before overwrite
    #pragma unroll
    for (int m = 0; m < 2; m++) {
        int rb = wave*32 + m*16 + lh*4;
        #pragma unroll
        for (int n = 0; n < 4; n++) {
            int c0 = n*16 + lr;
            int c1 = 64 + n*16 + lr;
            float b0 = bias_s[512 + c0];
            float b1 = bias_s[512 + c1];
            #pragma unroll
            for (int r = 0; r < 4; r++) {
                zb[(rb + r)*LDSP + c0] = f2bf(1.f / (1.f + __expf(-(G0[m][n][r] + b0))));
                zb[(rb + r)*LDSP + c1] = f2bf(1.f / (1.f + __expf(-(G1[m][n][r] + b1))));
            }
        }
    }
    __syncthreads();
    {
        const unsigned short* src = zb + tid2*LDSP + half*64;
        unsigned short* dst = g_out + (size_t)(pos0 + tid2)*CDIM + half*64;
        #pragma unroll
        for (int i = 0; i < 8; i++)
            *(short8*)(dst + i*8) = *(const short8*)(src + i*8);
    }
}

// ---------------- K2: per-channel einsum x[c] = A_c * B_c^T ----------------------
// Round-1 structure verbatim: 128x128 tile, K steps of 64, linear LDS staging.
__global__ __launch_bounds__(256, 2) void k2_einsum(
    const unsigned short* __restrict__ a_t,
    const unsigned short* __restrict__ b_t,
    unsigned short* __restrict__ x_t)
{
    __shared__ unsigned short As[128*64];
    __shared__ unsigned short Bs[128*64];

    const int c  = blockIdx.y;
    const int ti = (blockIdx.x >> 2) * 128;
    const int tj = (blockIdx.x & 3) * 128;
    const int t = threadIdx.x;
    const int wave = t >> 6, lane = t & 63;
    const int lr = lane & 15, lh = lane >> 4;
    const int wm = wave >> 1, wn = wave & 1;

    const unsigned short* Ag = a_t + (size_t)c*NN + (size_t)ti*NDIM;
    const unsigned short* Bg = b_t + (size_t)c*NN + (size_t)tj*NDIM;

    const int srow = wave*32 + (lane >> 3);  // staging row within tile
    const int scol = (lane & 7) * 8;         // staging k-offset (elems)

    f32x4 acc[4][4] = {};

    for (int k0 = 0; k0 < NDIM; k0 += 64) {
        __syncthreads();
        #pragma unroll
        for (int it = 0; it < 4; it++) {
            int r = srow + it*8;
            gl_lds16(Ag + (size_t)r*NDIM + k0 + scol, (void*)(As + (wave*32 + it*8)*64));
            gl_lds16(Bg + (size_t)r*NDIM + k0 + scol, (void*)(Bs + (wave*32 + it*8)*64));
        }
        asm volatile("s_waitcnt vmcnt(0)" ::: "memory");
        __syncthreads();
        #pragma unroll
        for (int kk = 0; kk < 2; kk++) {
            const int kof = kk*32 + lh*8;
            short8 af[4], bfr[4];
            #pragma unroll
            for (int m = 0; m < 4; m++)
                af[m] = *(const short8*)&As[(wm*64 + m*16 + lr)*64 + kof];
            #pragma unroll
            for (int n = 0; n < 4; n++)
                bfr[n] = *(const short8*)&Bs[(wn*64 + n*16 + lr)*64 + kof];
            #pragma unroll
            for (int m = 0; m < 4; m++)
                #pragma unroll
                for (int n = 0; n < 4; n++)
                    acc[m][n] = mfma16(af[m], bfr[n], acc[m][n]);
        }
    }

    #pragma unroll
    for (int m = 0; m < 4; m++) {
        int row = ti + wm*64 + m*16 + lh*4;
        #pragma unroll
        for (int n = 0; n < 4; n++) {
            int col = tj + wn*64 + n*16 + lr;
            unsigned short* dst = x_t + (size_t)c*NN + (size_t)row*NDIM + col;
            #pragma unroll
            for (int r = 0; r < 4; r++)
                dst[(size_t)r*NDIM] = f2bf(acc[m][n][r]);
        }
    }
}

// ---------------- K3: LN_out + output projection + gate (round-1 verbatim) -------
__global__ __launch_bounds__(256, 2) void k3_out(
    const unsigned short* __restrict__ x_t,
    const unsigned short* __restrict__ g_in,
    const unsigned short* __restrict__ Wo_t,
    const float* __restrict__ lnw, const float* __restrict__ lnb,
    const float* __restrict__ b_o,
    float* __restrict__ out)
{
    __shared__ unsigned short xb[128*LDSP];   // x tile [c][pos]; reused for Wo [col][k]
    __shared__ unsigned short zl[128*LDSP];   // LN'd x [pos][c]; reused for g [pos][c]
    __shared__ float lnw_s[128];
    __shared__ float lnb_s[128];
    __shared__ float bo_s[128];

    const int t = threadIdx.x;
    const int pos0 = blockIdx.x * 128;
    const int tid2 = t >> 1, half = t & 1;
    const int wave = t >> 6, lane = t & 63;
    const int lr = lane & 15, lh = lane >> 4;

    if (t < 128) { lnw_s[t] = lnw[t]; lnb_s[t] = lnb[t]; bo_s[t] = b_o[t]; }

    // stage x tile: thread pair per channel row, coalesced
    {
        const unsigned short* src = x_t + (size_t)tid2*NN + pos0 + half*64;
        unsigned short* dst = xb + tid2*LDSP + half*64;
        #pragma unroll
        for (int i = 0; i < 8; i++)
            *(short8*)(dst + i*8) = *(const short8*)(src + i*8);
    }
    __syncthreads();

    // LN over c: 2 threads per pos
    {
        float v[64];
        float s0 = 0.f, s1 = 0.f;
        #pragma unroll
        for (int i = 0; i < 64; i++) {
            float x = bf2f(xb[(half*64 + i)*LDSP + tid2]);
            v[i] = x; s0 += x; s1 += x*x;
        }
        s0 += __shfl_xor(s0, 1);
        s1 += __shfl_xor(s1, 1);
        float m  = s0 * (1.f/128.f);
        float va = s1 * (1.f/128.f) - m*m;
        float rs = rsqrtf(va + 1e-5f);
        #pragma unroll
        for (int i = 0; i < 64; i++) {
            int cc = half*64 + i;
            zl[tid2*LDSP + cc] = f2bf((v[i]-m)*rs*lnw_s[cc] + lnb_s[cc]);
        }
    }
    __syncthreads();

    // Wo into xb (alias; xb dead now)
    {
        const unsigned short* src = Wo_t + ((size_t)tid2*128 + half*64);
        unsigned short* dst = xb + tid2*LDSP + half*64;
        #pragma unroll
        for (int i = 0; i < 8; i++)
            *(short8*)(dst + i*8) = *(const short8*)(src + i*8);
    }
    __syncthreads();

    f32x4 acc[2][8];
    #pragma unroll
    for (int m = 0; m < 2; m++)
        #pragma unroll
        for (int n = 0; n < 8; n++) { f32x4 zz = {0.f,0.f,0.f,0.f}; acc[m][n] = zz; }

    #pragma unroll
    for (int kk = 0; kk < 4; kk++) {
        const int k0 = kk*32 + lh*8;
        short8 af0 = *(const short8*)&zl[(wave*32 + lr)*LDSP + k0];
        short8 af1 = *(const short8*)&zl[(wave*32 + 16 + lr)*LDSP + k0];
        #pragma unroll
        for (int n = 0; n < 8; n++) {
            short8 bf = *(const short8*)&xb[(n*16 + lr)*LDSP + k0];
            acc[0][n] = mfma16(af0, bf, acc[0][n]);
            acc[1][n] = mfma16(af1, bf, acc[1][n]);
        }
    }
    __syncthreads();

    // g into zl space (zl dead after GEMM)
    {
        const unsigned short* src = g_in + (size_t)(pos0 + tid2)*CDIM + half*64;
        unsigned short* dst = zl + tid2*LDSP + half*64;
        #pragma unroll
        for (int i = 0; i < 8; i++)
            *(short8*)(dst + i*8) = *(const short8*)(src + i*8);
    }
    __syncthreads();

    #pragma unroll
    for (int m = 0; m < 2; m++) {
        int rb = wave*32 + m*16 + lh*4;
        #pragma unroll
        for (int n = 0; n < 8; n++) {
            int col = n*16 + lr;
            float bo = bo_s[col];
            #pragma unroll
            for (int r = 0; r < 4; r++) {
                int row = rb + r;
                float gv = bf2f(zl[row*LDSP + col]);
                out[(size_t)(pos0 + row)*CDIM + col] = gv * (acc[m][n][r] + bo);
            }
        }
    }
}

// ---------------- launcher -------------------------------------------------------
extern "C" void kernel_launch(void* const* d_in, const int* in_sizes, int n_in,
                              void* d_out, int out_size, void* d_ws, size_t ws_size,
                              hipStream_t stream) {
    const float* z        = (const float*)d_in[0];
    const float* mask     = (const float*)d_in[1];
    const float* ln_in_w  = (const float*)d_in[2];
    const float* ln_in_b  = (const float*)d_in[3];
    const float* w_ap     = (const float*)d_in[4];
    const float* b_ap     = (const float*)d_in[5];
    const float* w_ag     = (const float*)d_in[6];
    const float* b_ag     = (const float*)d_in[7];
    const float* w_bp     = (const float*)d_in[8];
    const float* b_bp     = (const float*)d_in[9];
    const float* w_bg     = (const float*)d_in[10];
    const float* b_bg     = (const float*)d_in[11];
    const float* ln_out_w = (const float*)d_in[12];
    const float* ln_out_b = (const float*)d_in[13];
    const float* w_o      = (const float*)d_in[14];
    const float* b_o      = (const float*)d_in[15];
    const float* w_g      = (const float*)d_in[16];
    const float* b_g      = (const float*)d_in[17];

    char* ws = (char*)d_ws;
    const size_t BUF = (size_t)NN * 128 * 2;      // 64 MB per bf16 buffer
    unsigned short* a_t   = (unsigned short*)(ws);
    unsigned short* b_t   = (unsigned short*)(ws + BUF);
    unsigned short* g_b   = (unsigned short*)(ws + 2*BUF);
    unsigned short* x_t   = (unsigned short*)(ws + 3*BUF);
    unsigned short* Wfrag = (unsigned short*)(ws + 4*BUF);
    unsigned short* Wo_t  = (unsigned short*)(ws + 4*BUF + (size_t)10240*8*2);

    k0_prep<<<104, 256, 0, stream>>>(w_ag, w_ap, w_bg, w_bp, w_g, w_o, Wfrag, Wo_t);
    k1_proj<<<NN/128, 256, 0, stream>>>(z, mask, ln_in_w, ln_in_b, Wfrag,
                                        b_ag, b_ap, b_bg, b_bp, b_g, a_t, b_t, g_b);
    k2_einsum<<<dim3(16, 128), 256, 0, stream>>>(a_t, b_t, x_t);
    k3_out<<<NN/128, 256, 0, stream>>>(x_t, g_b, Wo_t, ln_out_w, ln_out_b, b_o,
                                       (float*)d_out);
}

// Round 8
// 307.415 us; speedup vs baseline: 1.2754x; 1.0765x over previous
//
#include <hip/hip_runtime.h>
#include <hip/hip_bf16.h>
#include <stdint.h>

#define NDIM 512
#define NN (NDIM*NDIM)      // 262144 positions
#define CDIM 128
#define LDSP 136            // padded LDS stride (bf16 elems): 272B, 16B-mult

typedef __attribute__((ext_vector_type(8))) short short8;
typedef __attribute__((ext_vector_type(4))) short short4v;
typedef __attribute__((ext_vector_type(4))) float f32x4;
typedef unsigned long long ull;

__device__ __forceinline__ unsigned short f2bf(float f) {
    union { float f; uint32_t u; } v; v.f = f;
    uint32_t u = v.u;
    return (unsigned short)((u + 0x7FFFu + ((u >> 16) & 1u)) >> 16);
}
__device__ __forceinline__ float bf2f(unsigned short b) {
    union { uint32_t u; float f; } v; v.u = ((uint32_t)b) << 16;
    return v.f;
}
__device__ __forceinline__ f32x4 mfma16(short8 a, short8 b, f32x4 c) {
    return __builtin_amdgcn_mfma_f32_16x16x32_bf16(a, b, c, 0, 0, 0);
}
__device__ __forceinline__ void gl_lds16(const void* g, void* l) {
    __builtin_amdgcn_global_load_lds((const __attribute__((address_space(1))) void*)g,
                                     (__attribute__((address_space(3))) void*)l,
                                     16, 0, 0);
}

// ---------------- K0: weight prep --------------------------------------------
// Wfrag: 5 proj matrices in MFMA-fragment order. Chunk idx = s*2048 + h*1024 +
// kk*256 + n*64 + lane; chunk holds w_s[k0+e][col], col=h*64+n*16+(lane&15),
// k0=kk*32+(lane>>4)*8, e=0..7.  K1 reads chunk-groups as coalesced 1KB/wave.
// Wo_t[c][h] = w_o[h][c] (round-6 layout, consumed by K3 verbatim).
__global__ void k0_prep(const float* __restrict__ w_ag, const float* __restrict__ w_ap,
                        const float* __restrict__ w_bg, const float* __restrict__ w_bp,
                        const float* __restrict__ w_g,  const float* __restrict__ w_o,
                        unsigned short* __restrict__ Wfrag, unsigned short* __restrict__ Wo_t)
{
    int idx = blockIdx.x * 256 + threadIdx.x;
    if (idx < 10240) {
        int lane = idx & 63;
        int n  = (idx >> 6) & 3;
        int kk = (idx >> 8) & 3;
        int h  = (idx >> 10) & 1;
        int s  = idx >> 11;          // 0..4
        const float* w = (s==0) ? w_ag : (s==1) ? w_ap : (s==2) ? w_bg : (s==3) ? w_bp : w_g;
        int col = h*64 + n*16 + (lane & 15);
        int k0  = kk*32 + (lane >> 4)*8;
        short8 pk;
        #pragma unroll
        for (int e = 0; e < 8; e++)
            pk[e] = (short)f2bf(w[(k0 + e)*128 + col]);
        *(short8*)(Wfrag + (size_t)idx*8) = pk;
    } else if (idx < 10240 + 16384) {
        int i2 = idx - 10240;
        int cc = i2 >> 7, hh = i2 & 127;
        Wo_t[i2] = f2bf(w_o[hh*128 + cc]);
    }
}

// ---------------- K1: LN_in + 5 projections + activations ------------------------
// out: a_t[c][pos], b_t[c][pos] (channel-major, shfl write-combined);
//      g_out[pos][c] (round-6 proven LDS-transpose path)
__global__ __launch_bounds__(256, 2) void k1_proj(
    const float* __restrict__ z, const float* __restrict__ mask,
    const float* __restrict__ lnw, const float* __restrict__ lnb,
    const unsigned short* __restrict__ Wfrag,
    const float* __restrict__ b_ag, const float* __restrict__ b_ap,
    const float* __restrict__ b_bg, const float* __restrict__ b_bp,
    const float* __restrict__ b_g,
    unsigned short* __restrict__ a_t, unsigned short* __restrict__ b_t,
    unsigned short* __restrict__ g_out)
{
    __shared__ unsigned short zb[128*LDSP];   // LN'd z [row][k]; reused as g transpose buf
    __shared__ float mask_s[128];
    __shared__ float lnw_s[128];
    __shared__ float lnb_s[128];
    __shared__ float bias_s[640];

    const int t = threadIdx.x;
    const int pos0 = blockIdx.x * 128;
    const int tid2 = t >> 1, half = t & 1;
    const int wave = t >> 6, lane = t & 63;
    const int lr = lane & 15, lh = lane >> 4;

    if (t < 128) {
        lnw_s[t] = lnw[t];
        lnb_s[t] = lnb[t];
        mask_s[t] = mask[pos0 + t];
    }
    for (int i = t; i < 640; i += 256) {
        int s = i >> 7, c = i & 127;
        const float* bp = (s==0) ? b_ag : (s==1) ? b_ap : (s==2) ? b_bg : (s==3) ? b_bp : b_g;
        bias_s[i] = bp[c];
    }

    // ---- load z (2 threads per row), LN over C ----
    float v[64];
    float s0 = 0.f, s1 = 0.f;
    {
        const float* zr = z + (size_t)(pos0 + tid2) * CDIM + half * 64;
        #pragma unroll
        for (int i = 0; i < 16; i++) {
            float4 q = *(const float4*)(zr + i*4);
            v[i*4+0] = q.x; v[i*4+1] = q.y; v[i*4+2] = q.z; v[i*4+3] = q.w;
        }
        #pragma unroll
        for (int i = 0; i < 64; i++) { s0 += v[i]; s1 += v[i]*v[i]; }
        s0 += __shfl_xor(s0, 1);
        s1 += __shfl_xor(s1, 1);
    }
    __syncthreads();   // lnw_s/lnb_s/bias/mask ready
    {
        float m  = s0 * (1.f/128.f);
        float va = s1 * (1.f/128.f) - m*m;
        float rs = rsqrtf(va + 1e-5f);
        #pragma unroll
        for (int i = 0; i < 8; i++) {
            short8 pk;
            #pragma unroll
            for (int j = 0; j < 8; j++) {
                int c = half*64 + i*8 + j;
                pk[j] = (short)f2bf((v[i*8+j]-m)*rs*lnw_s[c] + lnb_s[c]);
            }
            *(short8*)&zb[tid2*LDSP + half*64 + i*8] = pk;
        }
    }
    __syncthreads();   // zb ready

    const int rowA0 = (wave*32 + lr)*LDSP;
    const int rowA1 = (wave*32 + 16 + lr)*LDSP;
    const unsigned short* wfl = Wfrag + (size_t)lane*8;

    // GEMM over a 64-col half of one weight matrix: acc[2][4].
    // All 16 B-fragments batch-loaded first (static wbuf indices -> registers,
    // 16 back-to-back global_load_dwordx4, ONE vmcnt wait) then 32 MFMA.
    auto gemmh = [&](int s, int h, f32x4 (&acc)[2][4]) {
        const unsigned short* wf = wfl + (size_t)(s*2 + h)*8192;
        short8 wbuf[16];
        #pragma unroll
        for (int i = 0; i < 16; i++)
            wbuf[i] = *(const short8*)(wf + i*512);
        #pragma unroll
        for (int m = 0; m < 2; m++)
            #pragma unroll
            for (int n = 0; n < 4; n++) { f32x4 zz = {0.f,0.f,0.f,0.f}; acc[m][n] = zz; }
        #pragma unroll
        for (int kk = 0; kk < 4; kk++) {
            const int k0 = kk*32 + lh*8;
            short8 af0 = *(const short8*)&zb[rowA0 + k0];
            short8 af1 = *(const short8*)&zb[rowA1 + k0];
            #pragma unroll
            for (int n = 0; n < 4; n++) {
                acc[0][n] = mfma16(af0, wbuf[kk*4 + n], acc[0][n]);
                acc[1][n] = mfma16(af1, wbuf[kk*4 + n], acc[1][n]);
            }
        }
    };

    // gated pair -> dst[c][pos] channel-major; shfl_xor(16) write-combine so each
    // store instr covers full 64B lines per column (no partial-line writes).
    auto pair_half = [&](int sG, int sP, int h, unsigned short* dstg) {
        f32x4 G[2][4], P[2][4];
        gemmh(sG, h, G);
        gemmh(sP, h, P);
        const int odd = lh & 1;
        const int base = wave*32 + lh*4 + (odd ? 12 : 0);
        #pragma unroll
        for (int n = 0; n < 4; n++) {
            int col = h*64 + n*16 + lr;
            float bgv = bias_s[sG*128 + col];
            float bpv = bias_s[sP*128 + col];
            union { short4v v; ull u; } p0, p1;
            #pragma unroll
            for (int r = 0; r < 4; r++) {
                float g0 = 1.f / (1.f + __expf(-(G[0][n][r] + bgv)));
                p0.v[r] = (short)f2bf(mask_s[wave*32 + lh*4 + r] * g0 * (P[0][n][r] + bpv));
                float g1 = 1.f / (1.f + __expf(-(G[1][n][r] + bgv)));
                p1.v[r] = (short)f2bf(mask_s[wave*32 + 16 + lh*4 + r] * g1 * (P[1][n][r] + bpv));
            }
            ull r0 = __shfl_xor(p0.u, 16);
            ull r1 = __shfl_xor(p1.u, 16);
            union { ull u[2]; short8 v; } outv;
            outv.u[0] = odd ? r1 : p0.u;   // rows base..base+3
            outv.u[1] = odd ? p1.u : r0;   // rows base+4..base+7
            *(short8*)(dstg + (size_t)col*NN + pos0 + base) = outv.v;
        }
    };

    pair_half(0, 1, 0, a_t);
    pair_half(0, 1, 1, a_t);
    pair_half(2, 3, 0, b_t);
    pair_half(2, 3, 1, b_t);

    // gate g -> g_out[pos][c] via LDS transpose (round-6 proven path; zb reused)
    f32x4 G0[2][4], G1[2][4];
    gemmh(4, 0, G0);
    gemmh(4, 1, G1);
    __syncthreads();   // all zb reads complete block-wide before overwrite
    #pragma unroll
    for (int m = 0; m < 2; m++) {
        int rb = wave*32 + m*16 + lh*4;
        #pragma unroll
        for (int n = 0; n < 4; n++) {
            int c0 = n*16 + lr;
            int c1 = 64 + n*16 + lr;
            float b0 = bias_s[512 + c0];
            float b1 = bias_s[512 + c1];
            #pragma unroll
            for (int r = 0; r < 4; r++) {
                zb[(rb + r)*LDSP + c0] = f2bf(1.f / (1.f + __expf(-(G0[m][n][r] + b0))));
                zb[(rb + r)*LDSP + c1] = f2bf(1.f / (1.f + __expf(-(G1[m][n][r] + b1))));
            }
        }
    }
    __syncthreads();
    {
        const unsigned short* src = zb + tid2*LDSP + half*64;
        unsigned short* dst = g_out + (size_t)(pos0 + tid2)*CDIM + half*64;
        #pragma unroll
        for (int i = 0; i < 8; i++)
            *(short8*)(dst + i*8) = *(const short8*)(src + i*8);
    }
}

// ---------------- K2: per-channel einsum x[c] = A_c * B_c^T ----------------------
// Round-1 structure verbatim: 128x128 tile, K steps of 64, linear LDS staging.
__global__ __launch_bounds__(256, 2) void k2_einsum(
    const unsigned short* __restrict__ a_t,
    const unsigned short* __restrict__ b_t,
    unsigned short* __restrict__ x_t)
{
    __shared__ unsigned short As[128*64];
    __shared__ unsigned short Bs[128*64];

    const int c  = blockIdx.y;
    const int ti = (blockIdx.x >> 2) * 128;
    const int tj = (blockIdx.x & 3) * 128;
    const int t = threadIdx.x;
    const int wave = t >> 6, lane = t & 63;
    const int lr = lane & 15, lh = lane >> 4;
    const int wm = wave >> 1, wn = wave & 1;

    const unsigned short* Ag = a_t + (size_t)c*NN + (size_t)ti*NDIM;
    const unsigned short* Bg = b_t + (size_t)c*NN + (size_t)tj*NDIM;

    const int srow = wave*32 + (lane >> 3);  // staging row within tile
    const int scol = (lane & 7) * 8;         // staging k-offset (elems)

    f32x4 acc[4][4] = {};

    for (int k0 = 0; k0 < NDIM; k0 += 64) {
        __syncthreads();
        #pragma unroll
        for (int it = 0; it < 4; it++) {
            int r = srow + it*8;
            gl_lds16(Ag + (size_t)r*NDIM + k0 + scol, (void*)(As + (wave*32 + it*8)*64));
            gl_lds16(Bg + (size_t)r*NDIM + k0 + scol, (void*)(Bs + (wave*32 + it*8)*64));
        }
        asm volatile("s_waitcnt vmcnt(0)" ::: "memory");
        __syncthreads();
        #pragma unroll
        for (int kk = 0; kk < 2; kk++) {
            const int kof = kk*32 + lh*8;
            short8 af[4], bfr[4];
            #pragma unroll
            for (int m = 0; m < 4; m++)
                af[m] = *(const short8*)&As[(wm*64 + m*16 + lr)*64 + kof];
            #pragma unroll
            for (int n = 0; n < 4; n++)
                bfr[n] = *(const short8*)&Bs[(wn*64 + n*16 + lr)*64 + kof];
            #pragma unroll
            for (int m = 0; m < 4; m++)
                #pragma unroll
                for (int n = 0; n < 4; n++)
                    acc[m][n] = mfma16(af[m], bfr[n], acc[m][n]);
        }
    }

    #pragma unroll
    for (int m = 0; m < 4; m++) {
        int row = ti + wm*64 + m*16 + lh*4;
        #pragma unroll
        for (int n = 0; n < 4; n++) {
            int col = tj + wn*64 + n*16 + lr;
            unsigned short* dst = x_t + (size_t)c*NN + (size_t)row*NDIM + col;
            #pragma unroll
            for (int r = 0; r < 4; r++)
                dst[(size_t)r*NDIM] = f2bf(acc[m][n][r]);
        }
    }
}

// ---------------- K3: LN_out + output projection + gate (round-1 verbatim) -------
__global__ __launch_bounds__(256, 2) void k3_out(
    const unsigned short* __restrict__ x_t,
    const unsigned short* __restrict__ g_in,
    const unsigned short* __restrict__ Wo_t,
    const float* __restrict__ lnw, const float* __restrict__ lnb,
    const float* __restrict__ b_o,
    float* __restrict__ out)
{
    __shared__ unsigned short xb[128*LDSP];   // x tile [c][pos]; reused for Wo [col][k]
    __shared__ unsigned short zl[128*LDSP];   // LN'd x [pos][c]; reused for g [pos][c]
    __shared__ float lnw_s[128];
    __shared__ float lnb_s[128];
    __shared__ float bo_s[128];

    const int t = threadIdx.x;
    const int pos0 = blockIdx.x * 128;
    const int tid2 = t >> 1, half = t & 1;
    const int wave = t >> 6, lane = t & 63;
    const int lr = lane & 15, lh = lane >> 4;

    if (t < 128) { lnw_s[t] = lnw[t]; lnb_s[t] = lnb[t]; bo_s[t] = b_o[t]; }

    // stage x tile: thread pair per channel row, coalesced
    {
        const unsigned short* src = x_t + (size_t)tid2*NN + pos0 + half*64;
        unsigned short* dst = xb + tid2*LDSP + half*64;
        #pragma unroll
        for (int i = 0; i < 8; i++)
            *(short8*)(dst + i*8) = *(const short8*)(src + i*8);
    }
    __syncthreads();

    // LN over c: 2 threads per pos
    {
        float v[64];
        float s0 = 0.f, s1 = 0.f;
        #pragma unroll
        for (int i = 0; i < 64; i++) {
            float x = bf2f(xb[(half*64 + i)*LDSP + tid2]);
            v[i] = x; s0 += x; s1 += x*x;
        }
        s0 += __shfl_xor(s0, 1);
        s1 += __shfl_xor(s1, 1);
        float m  = s0 * (1.f/128.f);
        float va = s1 * (1.f/128.f) - m*m;
        float rs = rsqrtf(va + 1e-5f);
        #pragma unroll
        for (int i = 0; i < 64; i++) {
            int cc = half*64 + i;
            zl[tid2*LDSP + cc] = f2bf((v[i]-m)*rs*lnw_s[cc] + lnb_s[cc]);
        }
    }
    __syncthreads();

    // Wo into xb (alias; xb dead now)
    {
        const unsigned short* src = Wo_t + ((size_t)tid2*128 + half*64);
        unsigned short* dst = xb + tid2*LDSP + half*64;
        #pragma unroll
        for (int i = 0; i < 8; i++)
            *(short8*)(dst + i*8) = *(const short8*)(src + i*8);
    }
    __syncthreads();

    f32x4 acc[2][8];
    #pragma unroll
    for (int m = 0; m < 2; m++)
        #pragma unroll
        for (int n = 0; n < 8; n++) { f32x4 zz = {0.f,0.f,0.f,0.f}; acc[m][n] = zz; }

    #pragma unroll
    for (int kk = 0; kk < 4; kk++) {
        const int k0 = kk*32 + lh*8;
        short8 af0 = *(const short8*)&zl[(wave*32 + lr)*LDSP + k0];
        short8 af1 = *(const short8*)&zl[(wave*32 + 16 + lr)*LDSP + k0];
        #pragma unroll
        for (int n = 0; n < 8; n++) {
            short8 bf = *(const short8*)&xb[(n*16 + lr)*LDSP + k0];
            acc[0][n] = mfma16(af0, bf, acc[0][n]);
            acc[1][n] = mfma16(af1, bf, acc[1][n]);
        }
    }
    __syncthreads();

    // g into zl space (zl dead after GEMM)
    {
        const unsigned short* src = g_in + (size_t)(pos0 + tid2)*CDIM + half*64;
        unsigned short* dst = zl + tid2*LDSP + half*64;
        #pragma unroll
        for (int i = 0; i < 8; i++)
            *(short8*)(dst + i*8) = *(const short8*)(src + i*8);
    }
    __syncthreads();

    #pragma unroll
    for (int m = 0; m < 2; m++) {
        int rb = wave*32 + m*16 + lh*4;
        #pragma unroll
        for (int n = 0; n < 8; n++) {
            int col = n*16 + lr;
            float bo = bo_s[col];
            #pragma unroll
            for (int r = 0; r < 4; r++) {
                int row = rb + r;
                float gv = bf2f(zl[row*LDSP + col]);
                out[(size_t)(pos0 + row)*CDIM + col] = gv * (acc[m][n][r] + bo);
            }
        }
    }
}

// ---------------- launcher -------------------------------------------------------
extern "C" void kernel_launch(void* const* d_in, const int* in_sizes, int n_in,
                              void* d_out, int out_size, void* d_ws, size_t ws_size,
                              hipStream_t stream) {
    const float* z        = (const float*)d_in[0];
    const float* mask     = (const float*)d_in[1];
    const float* ln_in_w  = (const float*)d_in[2];
    const float* ln_in_b  = (const float*)d_in[3];
    const float* w_ap     = (const float*)d_in[4];
    const float* b_ap     = (const float*)d_in[5];
    const float* w_ag     = (const float*)d_in[6];
    const float* b_ag     = (const float*)d_in[7];
    const float* w_bp     = (const float*)d_in[8];
    const float* b_bp     = (const float*)d_in[9];
    const float* w_bg     = (const float*)d_in[10];
    const float* b_bg     = (const float*)d_in[11];
    const float* ln_out_w = (const float*)d_in[12];
    const float* ln_out_b = (const float*)d_in[13];
    const float* w_o      = (const float*)d_in[14];
    const float* b_o      = (const float*)d_in[15];
    const float* w_g      = (const float*)d_in[16];
    const float* b_g      = (const float*)d_in[17];

    char* ws = (char*)d_ws;
    const size_t BUF = (size_t)NN * 128 * 2;      // 64 MB per bf16 buffer
    unsigned short* a_t   = (unsigned short*)(ws);
    unsigned short* b_t   = (unsigned short*)(ws + BUF);
    unsigned short* g_b   = (unsigned short*)(ws + 2*BUF);
    unsigned short* x_t   = (unsigned short*)(ws + 3*BUF);
    unsigned short* Wfrag = (unsigned short*)(ws + 4*BUF);
    unsigned short* Wo_t  = (unsigned short*)(ws + 4*BUF + (size_t)10240*8*2);

    k0_prep<<<104, 256, 0, stream>>>(w_ag, w_ap, w_bg, w_bp, w_g, w_o, Wfrag, Wo_t);
    k1_proj<<<NN/128, 256, 0, stream>>>(z, mask, ln_in_w, ln_in_b, Wfrag,
                                        b_ag, b_ap, b_bg, b_bp, b_g, a_t, b_t, g_b);
    k2_einsum<<<dim3(16, 128), 256, 0, stream>>>(a_t, b_t, x_t);
    k3_out<<<NN/128, 256, 0, stream>>>(x_t, g_b, Wo_t, ln_out_w, ln_out_b, b_o,
                                       (float*)d_out);
}